// Round 8
// baseline (395.393 us; speedup 1.0000x reference)
//
#include <hip/hip_runtime.h>
#include <cmath>

#define NN 10000
#define DINX 128
#define DHX 512
#define EE 160000
#define TOTE (EE + NN)
#define DOUTX 16
#define BN_EPS 1e-5f

// ---------------------------------------------------------------- GEMM v3
// C[M,Nn] = (A∘BN?)[M,K] @ B[K,Nn] + bias (optional relu). K mult of 32,
// Nn mult of 4. 128x64 tile, 256 threads, thread owns 8x4 outputs:
// per kk = 3x ds_read_b128 (36cy) vs 32 FMA (64cy) -> FMA-bound.
// Flat grid with XCD-grouped swizzle: bid&7 = XCD slot owns whole m-strips
// so the A-strip is fetched into that XCD's L2 ONCE for all its n-blocks.
template <bool RELU, bool BNA>
__global__ void gemm3_kernel(const float* __restrict__ A, const float* __restrict__ B,
                             const float* __restrict__ bias,
                             const float* __restrict__ sA, const float* __restrict__ tA,
                             float* __restrict__ C, int M, int K, int Nn,
                             int mB, int nB) {
    const int bid = blockIdx.x;
    const int x = bid & 7;
    const int rest = bid >> 3;
    const int sg = rest / nB;
    const int nblk = rest - sg * nB;
    const int mstrip = x + (sg << 3);
    if (mstrip >= mB) return;
    const int mBase = mstrip * 128;
    const int nBase = nblk * 64;

    __shared__ float As[32][132];  // [k][m], 132*4B stride (16B-aligned rows)
    __shared__ float Bs[32][68];   // [k][n]
    const int t = threadIdx.x;
    const int tx = t & 15, ty = t >> 4;

    float acc[8][4] = {};
    for (int k0 = 0; k0 < K; k0 += 32) {
        // A tile: 128(m) x 32(k) = 1024 float4, 4 per thread
        #pragma unroll
        for (int i = 0; i < 4; i++) {
            int idx = t + i * 256;
            int r = idx >> 3;           // m 0..127
            int c4 = idx & 7;           // k-group
            int gm = mBase + r;
            int kc = k0 + c4 * 4;
            float4 v = {0.f, 0.f, 0.f, 0.f};
            if (gm < M) v = *(const float4*)&A[(size_t)gm * K + kc];
            if (BNA) {
                v.x = v.x * sA[kc + 0] + tA[kc + 0];
                v.y = v.y * sA[kc + 1] + tA[kc + 1];
                v.z = v.z * sA[kc + 2] + tA[kc + 2];
                v.w = v.w * sA[kc + 3] + tA[kc + 3];
            }
            As[c4 * 4 + 0][r] = v.x;
            As[c4 * 4 + 1][r] = v.y;
            As[c4 * 4 + 2][r] = v.z;
            As[c4 * 4 + 3][r] = v.w;
        }
        // B tile: 32(k) x 64(n) = 512 float4, 2 per thread
        #pragma unroll
        for (int i = 0; i < 2; i++) {
            int idx = t + i * 256;
            int kr = idx >> 4;
            int nc4 = idx & 15;
            int gn = nBase + nc4 * 4;
            float4 v = {0.f, 0.f, 0.f, 0.f};
            if (gn + 3 < Nn) v = *(const float4*)&B[(size_t)(k0 + kr) * Nn + gn];
            *(float4*)&Bs[kr][nc4 * 4] = v;
        }
        __syncthreads();
        #pragma unroll
        for (int kk = 0; kk < 32; kk++) {
            float4 a0 = *(const float4*)&As[kk][ty * 8];
            float4 a1 = *(const float4*)&As[kk][ty * 8 + 4];
            float4 b  = *(const float4*)&Bs[kk][tx * 4];
            float av[8] = {a0.x, a0.y, a0.z, a0.w, a1.x, a1.y, a1.z, a1.w};
            float bv[4] = {b.x, b.y, b.z, b.w};
            #pragma unroll
            for (int i = 0; i < 8; i++)
                #pragma unroll
                for (int j = 0; j < 4; j++) acc[i][j] += av[i] * bv[j];
        }
        __syncthreads();
    }
    const int gn0 = nBase + tx * 4;
    #pragma unroll
    for (int i = 0; i < 8; i++) {
        int gm = mBase + ty * 8 + i;
        if (gm >= M) continue;
        if (gn0 + 3 < Nn) {
            float4 v;
            v.x = acc[i][0] + bias[gn0 + 0];
            v.y = acc[i][1] + bias[gn0 + 1];
            v.z = acc[i][2] + bias[gn0 + 2];
            v.w = acc[i][3] + bias[gn0 + 3];
            if (RELU) {
                v.x = fmaxf(v.x, 0.f); v.y = fmaxf(v.y, 0.f);
                v.z = fmaxf(v.z, 0.f); v.w = fmaxf(v.w, 0.f);
            }
            *(float4*)&C[(size_t)gm * Nn + gn0] = v;
        } else {
            #pragma unroll
            for (int j = 0; j < 4; j++) {
                int gn = gn0 + j;
                if (gn >= Nn) continue;
                float v = acc[i][j] + bias[gn];
                if (RELU) v = fmaxf(v, 0.f);
                C[(size_t)gm * Nn + gn] = v;
            }
        }
    }
}

// ---------------------------------------------------------------- CSR build
__global__ void deg_kernel(const int* __restrict__ dst, int* __restrict__ deg) {
    int i = blockIdx.x * 256 + threadIdx.x;
    if (i >= TOTE) return;
    int d = (i < EE) ? dst[i] : (i - EE);
    atomicAdd(&deg[d], 1);
}

// Register-blocked single-block scan: 1024 threads x 10 elements each.
#define SCAN_PER 10
__global__ void scan_kernel(const int* __restrict__ deg, int* __restrict__ off,
                            int* __restrict__ cur, int n) {
    const int t = threadIdx.x;          // 0..1023
    const int lane = t & 63, w = t >> 6;
    const int base = t * SCAN_PER;
    int v[SCAN_PER];
    int s = 0;
    #pragma unroll
    for (int i = 0; i < SCAN_PER; i++) {
        int idx = base + i;
        int d = (idx < n) ? deg[idx] : 0;
        s += d;
        v[i] = s;                        // per-thread inclusive scan
    }
    int x = s;
    #pragma unroll
    for (int sh = 1; sh < 64; sh <<= 1) {
        int y = __shfl_up(x, sh, 64);
        if (lane >= sh) x += y;
    }
    __shared__ int wsum[16];
    if (lane == 63) wsum[w] = x;
    __syncthreads();
    int wpre = 0;
    for (int i = 0; i < w; i++) wpre += wsum[i];
    const int excl = wpre + x - s;
    #pragma unroll
    for (int i = 0; i < SCAN_PER; i++) {
        int idx = base + i;
        if (idx < n) {
            off[idx + 1] = excl + v[i];
            cur[idx] = excl + (i ? v[i - 1] : 0);
        }
    }
    if (t == 0) off[0] = 0;
}

__global__ void scatter_kernel(const int* __restrict__ src, const int* __restrict__ dst,
                               int* __restrict__ cur, int* __restrict__ csr) {
    int i = blockIdx.x * 256 + threadIdx.x;
    if (i >= TOTE) return;
    int s = (i < EE) ? src[i] : (i - EE);
    int d = (i < EE) ? dst[i] : (i - EE);
    int pos = atomicAdd(&cur[d], 1);
    csr[pos] = s;
}

// ---------------------------------------------------------------- GAT node kernel
// ONE WAVE PER NODE, fused online softmax, 1-deep software prefetch of the
// next edge's source row: the gather for edge e+1 is issued before the
// shfl-reduce + softmax math of edge e, hiding ~300cy of L2/L3 latency.
#define GAT_WPB 4
__global__ void gat_node_kernel(const float* __restrict__ xl, const float* __restrict__ xr,
                                const float* __restrict__ att, const float* __restrict__ bias,
                                const int* __restrict__ off, const int* __restrict__ csr,
                                float* __restrict__ h) {
    const int wave = threadIdx.x >> 6;
    const int lane = threadIdx.x & 63;
    const int n = blockIdx.x * GAT_WPB + wave;
    if (n >= NN) return;

    const float4* xr4 = (const float4*)(xr + (size_t)n * DHX);
    const float4* att4 = (const float4*)att;
    const float4 xr0 = xr4[lane],      xr1 = xr4[lane + 64];
    const float4 at0 = att4[lane],     at1 = att4[lane + 64];

    const int o0 = off[n], o1 = off[n + 1];

    float4 a0 = {0.f, 0.f, 0.f, 0.f}, a1 = {0.f, 0.f, 0.f, 0.f};
    float m = -INFINITY, den = 0.f;

    // prefetch first edge
    {
        const int s0 = csr[o0];
        const float4* p0 = (const float4*)(xl + (size_t)s0 * DHX);
        a0 = a0;  // no-op
        float4 nx0 = p0[lane], nx1 = p0[lane + 64];
        for (int e = o0; e < o1; e++) {
            const float4 x0 = nx0, x1 = nx1;
            if (e + 1 < o1) {
                const int s2 = csr[e + 1];
                const float4* p2 = (const float4*)(xl + (size_t)s2 * DHX);
                nx0 = p2[lane];
                nx1 = p2[lane + 64];
            }
            // leaky_relu(xl[s] + xr[n]) . att  (partial per lane)
            float v;
            {
                float4 l0, l1;
                l0.x = x0.x + xr0.x; l0.y = x0.y + xr0.y; l0.z = x0.z + xr0.z; l0.w = x0.w + xr0.w;
                l1.x = x1.x + xr1.x; l1.y = x1.y + xr1.y; l1.z = x1.z + xr1.z; l1.w = x1.w + xr1.w;
                l0.x = (l0.x > 0.f) ? l0.x : 0.2f * l0.x;
                l0.y = (l0.y > 0.f) ? l0.y : 0.2f * l0.y;
                l0.z = (l0.z > 0.f) ? l0.z : 0.2f * l0.z;
                l0.w = (l0.w > 0.f) ? l0.w : 0.2f * l0.w;
                l1.x = (l1.x > 0.f) ? l1.x : 0.2f * l1.x;
                l1.y = (l1.y > 0.f) ? l1.y : 0.2f * l1.y;
                l1.z = (l1.z > 0.f) ? l1.z : 0.2f * l1.z;
                l1.w = (l1.w > 0.f) ? l1.w : 0.2f * l1.w;
                v  = l0.x * at0.x + l0.y * at0.y + l0.z * at0.z + l0.w * at0.w;
                v += l1.x * at1.x + l1.y * at1.y + l1.z * at1.z + l1.w * at1.w;
            }
            #pragma unroll
            for (int sft = 32; sft; sft >>= 1) v += __shfl_xor(v, sft, 64);
            // online softmax update (v wave-uniform -> uniform branch)
            if (v > m) {
                const float r = expf(m - v);   // first edge: exp(-inf) = 0
                den *= r;
                a0.x *= r; a0.y *= r; a0.z *= r; a0.w *= r;
                a1.x *= r; a1.y *= r; a1.z *= r; a1.w *= r;
                m = v;
            }
            const float p = expf(v - m);
            den += p;
            a0.x += p * x0.x; a0.y += p * x0.y; a0.z += p * x0.z; a0.w += p * x0.w;
            a1.x += p * x1.x; a1.y += p * x1.y; a1.z += p * x1.z; a1.w += p * x1.w;
        }
    }

    const float inv = 1.f / den;
    const float4 b0 = ((const float4*)bias)[lane];
    const float4 b1 = ((const float4*)bias)[lane + 64];
    float4 o0v, o1v;
    o0v.x = fmaxf(a0.x * inv + b0.x, 0.f);
    o0v.y = fmaxf(a0.y * inv + b0.y, 0.f);
    o0v.z = fmaxf(a0.z * inv + b0.z, 0.f);
    o0v.w = fmaxf(a0.w * inv + b0.w, 0.f);
    o1v.x = fmaxf(a1.x * inv + b1.x, 0.f);
    o1v.y = fmaxf(a1.y * inv + b1.y, 0.f);
    o1v.z = fmaxf(a1.z * inv + b1.z, 0.f);
    o1v.w = fmaxf(a1.w * inv + b1.w, 0.f);
    float4* h4 = (float4*)(h + (size_t)n * DHX);
    h4[lane] = o0v;
    h4[lane + 64] = o1v;
}

// ---------------------------------------------------------------- BatchNorm stats
// 625 blocks x 16 rows, float4 loads, LDS combine -> 1 partial slot/block.
#define BN_GRID 625   // NN / 16
template <int C>
__global__ void bn_stats_kernel(const float* __restrict__ x, float* __restrict__ partial) {
    constexpr int G = C / 4;
    constexpr int S = 256 / G;
    constexpr int IT = 16 / S;
    const int t = threadIdx.x;
    const int cg = t & (G - 1);
    const int sub = t / G;
    const size_t r0 = (size_t)blockIdx.x * 16 + sub;
    float4 s = {0.f, 0.f, 0.f, 0.f}, q = {0.f, 0.f, 0.f, 0.f};
    #pragma unroll
    for (int i = 0; i < IT; i++) {
        const float4 v = *(const float4*)&x[(r0 + (size_t)i * S) * C + cg * 4];
        s.x += v.x; s.y += v.y; s.z += v.z; s.w += v.w;
        q.x += v.x * v.x; q.y += v.y * v.y; q.z += v.z * v.z; q.w += v.w * v.w;
    }
    __shared__ float ls[2048];
    float* lsub = ls + sub * 2 * C;
    *(float4*)&lsub[cg * 4] = s;
    *(float4*)&lsub[C + cg * 4] = q;
    __syncthreads();
    for (int k = t; k < 2 * C; k += 256) {
        float acc = 0.f;
        #pragma unroll
        for (int ss = 0; ss < S; ss++) acc += ls[ss * 2 * C + k];
        partial[(size_t)blockIdx.x * 2 * C + k] = acc;
    }
}

// one block per channel; 256 threads reduce 625 partial slots.
template <int C>
__global__ void bn_affine_kernel(const float* __restrict__ partial,
                                 const float* __restrict__ g, const float* __restrict__ b,
                                 float* __restrict__ scale, float* __restrict__ shift,
                                 float invM) {
    const int c = blockIdx.x;
    const int t = threadIdx.x;
    float s = 0.f, q = 0.f;
    for (int p = t; p < BN_GRID; p += 256) {
        s += partial[(size_t)p * 2 * C + c];
        q += partial[(size_t)p * 2 * C + C + c];
    }
    #pragma unroll
    for (int sh = 32; sh; sh >>= 1) {
        s += __shfl_xor(s, sh, 64);
        q += __shfl_xor(q, sh, 64);
    }
    __shared__ float ws[8];
    const int lane = t & 63, w = t >> 6;
    if (lane == 0) { ws[w] = s; ws[4 + w] = q; }
    __syncthreads();
    if (t == 0) {
        s = ws[0] + ws[1] + ws[2] + ws[3];
        q = ws[4] + ws[5] + ws[6] + ws[7];
        float mu = s * invM;
        float var = q * invM - mu * mu;
        float sc = g[c] * rsqrtf(var + BN_EPS);
        scale[c] = sc;
        shift[c] = b[c] - mu * sc;
    }
}

// ---------------------------------------------------------------- head output
__global__ void head_out_kernel(const float* __restrict__ z3, float* __restrict__ out, int M) {
    int r = blockIdx.x * 256 + threadIdx.x;
    if (r >= M) return;
    float v[DOUTX];
    float mx = -INFINITY;
    #pragma unroll
    for (int i = 0; i < DOUTX; i++) { v[i] = z3[(size_t)r * DOUTX + i]; mx = fmaxf(mx, v[i]); }
    float s = 0.f;
    #pragma unroll
    for (int i = 0; i < DOUTX; i++) s += expf(v[i] - mx);
    float lse = mx + logf(s);
    #pragma unroll
    for (int i = 0; i < DOUTX; i++) out[(size_t)r * DOUTX + i] = 1.f / (1.f + expf(-v[i]));
    #pragma unroll
    for (int i = 0; i < DOUTX; i++) out[(size_t)(M * DOUTX) + (size_t)r * DOUTX + i] = v[i] - lse;
}

// ---------------------------------------------------------------- launch
extern "C" void kernel_launch(void* const* d_in, const int* in_sizes, int n_in,
                              void* d_out, int out_size, void* d_ws, size_t ws_size,
                              hipStream_t stream) {
    // Only stream-1 inputs are live (stream 0's h is overwritten; pooling/batch/train dead).
    const float* data1  = (const float*)d_in[11];
    const int*   ei1    = (const int*)d_in[12];   // [2, E]: row0 = src, row1 = dst
    const float* Wl1    = (const float*)d_in[14];
    const float* bl1    = (const float*)d_in[15];
    const float* Wr1    = (const float*)d_in[16];
    const float* br1    = (const float*)d_in[17];
    const float* att1   = (const float*)d_in[18];
    const float* bias1  = (const float*)d_in[19];
    const float* gamma1 = (const float*)d_in[20];
    const float* beta1  = (const float*)d_in[21];
    const float* W1  = (const float*)d_in[22];
    const float* b1  = (const float*)d_in[23];
    const float* g1  = (const float*)d_in[24];
    const float* be1 = (const float*)d_in[25];
    const float* W2  = (const float*)d_in[26];
    const float* b2  = (const float*)d_in[27];
    const float* g2  = (const float*)d_in[28];
    const float* be2 = (const float*)d_in[29];
    const float* W3  = (const float*)d_in[30];
    const float* b3  = (const float*)d_in[31];

    const int* e_src = ei1;
    const int* e_dst = ei1 + EE;

    // ---- workspace layout (floats)
    float* fws = (float*)d_ws;
    float* xl = fws;                         // 5,120,000
    float* xr = fws + 5120000;               // 5,120,000
    float* h  = fws + 10240000;              // 5,120,000
    int* ibase = (int*)(fws + 15360000);
    int* deg   = ibase;                      // 10,000
    int* offs  = ibase + 10000;              // 10,001
    int* cur   = ibase + 20016;              // 10,000
    int* csr   = ibase + 30016;              // 170,000
    float* scale   = fws + 15625600;         // 512
    float* shift   = fws + 15626112;         // 512
    // aliases (producers/consumers don't overlap in time)
    float* z1 = xr;                          // [10000,256]
    float* z2 = xl;                          // [10000,128]
    float* z3 = xl + 4000000;                // [10000,16]
    float* part_h  = xl;                     // BN(h):  xl consumed by gat; z2 not yet written
    float* part_z1 = xl;                     // BN(z1): read before z2 GEMM writes xl
    float* part_z2 = h;                      // BN(z2): h consumed by z1 GEMM already
    float* out = (float*)d_out;

    dim3 blk(256);
    const int mB = (NN + 127) / 128;         // 79 m-strips
    const int sgc = (mB + 7) / 8;            // 10 strip-groups per XCD slot

    // ---- xl = x @ Wl + bl ; xr = x @ Wr + br   (K=128, N=512, nB=8)
    hipLaunchKernelGGL((gemm3_kernel<false, false>), dim3(8 * sgc * 8), blk, 0, stream,
                       data1, Wl1, bl1, nullptr, nullptr, xl, NN, DINX, DHX, mB, 8);
    hipLaunchKernelGGL((gemm3_kernel<false, false>), dim3(8 * sgc * 8), blk, 0, stream,
                       data1, Wr1, br1, nullptr, nullptr, xr, NN, DINX, DHX, mB, 8);

    // ---- CSR by destination (incl. self-loops)
    hipMemsetAsync(deg, 0, NN * sizeof(int), stream);
    hipLaunchKernelGGL(deg_kernel, dim3((TOTE + 255) / 256), blk, 0, stream, e_dst, deg);
    hipLaunchKernelGGL(scan_kernel, dim3(1), dim3(1024), 0, stream, deg, offs, cur, NN);
    hipLaunchKernelGGL(scatter_kernel, dim3((TOTE + 255) / 256), blk, 0, stream, e_src, e_dst, cur, csr);

    // ---- GATv2 aggregation + bias + relu -> h (one wave per node, prefetched)
    hipLaunchKernelGGL(gat_node_kernel, dim3((NN + GAT_WPB - 1) / GAT_WPB), blk, 0, stream,
                       xl, xr, att1, bias1, offs, csr, h);

    // ---- BN(h) stats -> scale/shift (application fused into next GEMM)
    hipLaunchKernelGGL((bn_stats_kernel<512>), dim3(BN_GRID), blk, 0, stream, h, part_h);
    hipLaunchKernelGGL((bn_affine_kernel<512>), dim3(512), blk, 0, stream, part_h, gamma1, beta1, scale, shift, 1.f / NN);

    // ---- z1 = relu((h∘BN) @ W1 + b1)   (K=512, N=256, nB=4)
    hipLaunchKernelGGL((gemm3_kernel<true, true>), dim3(8 * sgc * 4), blk, 0, stream,
                       h, W1, b1, scale, shift, z1, NN, 512, 256, mB, 4);
    hipLaunchKernelGGL((bn_stats_kernel<256>), dim3(BN_GRID), blk, 0, stream, z1, part_z1);
    hipLaunchKernelGGL((bn_affine_kernel<256>), dim3(256), blk, 0, stream, part_z1, g1, be1, scale, shift, 1.f / NN);

    // ---- z2 = relu((z1∘BN) @ W2 + b2)   (K=256, N=128, nB=2)
    hipLaunchKernelGGL((gemm3_kernel<true, true>), dim3(8 * sgc * 2), blk, 0, stream,
                       z1, W2, b2, scale, shift, z2, NN, 256, 128, mB, 2);
    hipLaunchKernelGGL((bn_stats_kernel<128>), dim3(BN_GRID), blk, 0, stream, z2, part_z2);
    hipLaunchKernelGGL((bn_affine_kernel<128>), dim3(128), blk, 0, stream, part_z2, g2, be2, scale, shift, 1.f / NN);

    // ---- z3 = (z2∘BN) @ W3 + b3 ; sigmoid + log_softmax   (K=128, N=16, nB=1)
    hipLaunchKernelGGL((gemm3_kernel<false, true>), dim3(8 * sgc * 1), blk, 0, stream,
                       z2, W3, b3, scale, shift, z3, NN, 128, DOUTX, mB, 1);
    hipLaunchKernelGGL(head_out_kernel, dim3((NN + 255) / 256), blk, 0, stream, z3, out, NN);

    (void)in_sizes; (void)n_in; (void)out_size; (void)ws_size;
}

// Round 12
// 366.741 us; speedup vs baseline: 1.0781x; 1.0781x over previous
//
#include <hip/hip_runtime.h>
#include <cmath>

#define NN 10000
#define DINX 128
#define DHX 512
#define EE 160000
#define TOTE (EE + NN)
#define DOUTX 16
#define BN_EPS 1e-5f

// ---------------------------------------------------------------- GEMM v4
// C[M,Nn] = (A∘BN?)[M,K] @ B[K,Nn] + bias (optional relu). K mult of 32.
// 64x64 tile, 256 threads, 4x4 contiguous outputs/thread (2x ds_read_b128/kk).
// XCD-grouped flat grid (bid&7 owns whole m-strips -> A-strip lives in that
// XCD's L2 across its n-blocks) + register prefetch double-buffer: tile k0+1
// global loads issue right after the barrier, before tile k0's FMAs.
template <bool RELU, bool BNA>
__global__ void gemm4_kernel(const float* __restrict__ A, const float* __restrict__ B,
                             const float* __restrict__ bias,
                             const float* __restrict__ sA, const float* __restrict__ tA,
                             float* __restrict__ C, int M, int K, int Nn,
                             int mB, int nB) {
    const int bid = blockIdx.x;
    const int x = bid & 7;
    const int rest = bid >> 3;
    const int sg = rest / nB;
    const int nblk = rest - sg * nB;
    const int mstrip = x + (sg << 3);
    if (mstrip >= mB) return;
    const int mBase = mstrip * 64;
    const int nBase = nblk * 64;

    __shared__ float As[32][68];   // [k][m]
    __shared__ float Bs[32][68];   // [k][n]
    const int t = threadIdx.x;
    const int tx = t & 15, ty = t >> 4;

    float4 ra[2], rb[2];

    auto loadA = [&](int k0, int i) -> float4 {
        int idx = t + i * 256;
        int r = idx >> 3;           // m 0..63
        int c4 = idx & 7;           // k-group
        int gm = mBase + r;
        int kc = k0 + c4 * 4;
        float4 v = {0.f, 0.f, 0.f, 0.f};
        if (gm < M) v = *(const float4*)&A[(size_t)gm * K + kc];
        if (BNA) {
            v.x = v.x * sA[kc + 0] + tA[kc + 0];
            v.y = v.y * sA[kc + 1] + tA[kc + 1];
            v.z = v.z * sA[kc + 2] + tA[kc + 2];
            v.w = v.w * sA[kc + 3] + tA[kc + 3];
        }
        return v;
    };
    auto loadB = [&](int k0, int i) -> float4 {
        int idx = t + i * 256;
        int kr = idx >> 4;          // k 0..31
        int nc4 = idx & 15;         // n-group
        int gn = nBase + nc4 * 4;
        float4 v = {0.f, 0.f, 0.f, 0.f};
        if (gn + 3 < Nn) v = *(const float4*)&B[(size_t)(k0 + kr) * Nn + gn];
        return v;
    };

    // prefetch tile 0
    #pragma unroll
    for (int i = 0; i < 2; i++) { ra[i] = loadA(0, i); rb[i] = loadB(0, i); }

    float acc[4][4] = {};
    for (int k0 = 0; k0 < K; k0 += 32) {
        // write staged registers to LDS
        #pragma unroll
        for (int i = 0; i < 2; i++) {
            int idx = t + i * 256;
            int r = idx >> 3, c4 = idx & 7;
            As[c4 * 4 + 0][r] = ra[i].x;
            As[c4 * 4 + 1][r] = ra[i].y;
            As[c4 * 4 + 2][r] = ra[i].z;
            As[c4 * 4 + 3][r] = ra[i].w;
        }
        #pragma unroll
        for (int i = 0; i < 2; i++) {
            int idx = t + i * 256;
            int kr = idx >> 4, nc4 = idx & 15;
            *(float4*)&Bs[kr][nc4 * 4] = rb[i];
        }
        __syncthreads();
        // issue next tile's global loads (latency hides under FMAs below)
        if (k0 + 32 < K) {
            #pragma unroll
            for (int i = 0; i < 2; i++) { ra[i] = loadA(k0 + 32, i); rb[i] = loadB(k0 + 32, i); }
        }
        // compute
        #pragma unroll
        for (int kk = 0; kk < 32; kk++) {
            float4 a = *(const float4*)&As[kk][ty * 4];
            float4 b = *(const float4*)&Bs[kk][tx * 4];
            float av[4] = {a.x, a.y, a.z, a.w};
            float bv[4] = {b.x, b.y, b.z, b.w};
            #pragma unroll
            for (int i = 0; i < 4; i++)
                #pragma unroll
                for (int j = 0; j < 4; j++) acc[i][j] += av[i] * bv[j];
        }
        __syncthreads();
    }
    const int gn0 = nBase + tx * 4;
    #pragma unroll
    for (int i = 0; i < 4; i++) {
        int gm = mBase + ty * 4 + i;
        if (gm >= M) continue;
        if (gn0 + 3 < Nn) {
            float4 v;
            v.x = acc[i][0] + bias[gn0 + 0];
            v.y = acc[i][1] + bias[gn0 + 1];
            v.z = acc[i][2] + bias[gn0 + 2];
            v.w = acc[i][3] + bias[gn0 + 3];
            if (RELU) {
                v.x = fmaxf(v.x, 0.f); v.y = fmaxf(v.y, 0.f);
                v.z = fmaxf(v.z, 0.f); v.w = fmaxf(v.w, 0.f);
            }
            *(float4*)&C[(size_t)gm * Nn + gn0] = v;
        } else {
            #pragma unroll
            for (int j = 0; j < 4; j++) {
                int gn = gn0 + j;
                if (gn >= Nn) continue;
                float v = acc[i][j] + bias[gn];
                if (RELU) v = fmaxf(v, 0.f);
                C[(size_t)gm * Nn + gn] = v;
            }
        }
    }
}

// ---------------------------------------------------------------- CSR build
__global__ void deg_kernel(const int* __restrict__ dst, int* __restrict__ deg) {
    int i = blockIdx.x * 256 + threadIdx.x;
    if (i >= TOTE) return;
    int d = (i < EE) ? dst[i] : (i - EE);
    atomicAdd(&deg[d], 1);
}

// Register-blocked single-block scan: 1024 threads x 10 elements each.
#define SCAN_PER 10
__global__ void scan_kernel(const int* __restrict__ deg, int* __restrict__ off,
                            int* __restrict__ cur, int n) {
    const int t = threadIdx.x;          // 0..1023
    const int lane = t & 63, w = t >> 6;
    const int base = t * SCAN_PER;
    int v[SCAN_PER];
    int s = 0;
    #pragma unroll
    for (int i = 0; i < SCAN_PER; i++) {
        int idx = base + i;
        int d = (idx < n) ? deg[idx] : 0;
        s += d;
        v[i] = s;                        // per-thread inclusive scan
    }
    int x = s;
    #pragma unroll
    for (int sh = 1; sh < 64; sh <<= 1) {
        int y = __shfl_up(x, sh, 64);
        if (lane >= sh) x += y;
    }
    __shared__ int wsum[16];
    if (lane == 63) wsum[w] = x;
    __syncthreads();
    int wpre = 0;
    for (int i = 0; i < w; i++) wpre += wsum[i];
    const int excl = wpre + x - s;
    #pragma unroll
    for (int i = 0; i < SCAN_PER; i++) {
        int idx = base + i;
        if (idx < n) {
            off[idx + 1] = excl + v[i];
            cur[idx] = excl + (i ? v[i - 1] : 0);
        }
    }
    if (t == 0) off[0] = 0;
}

__global__ void scatter_kernel(const int* __restrict__ src, const int* __restrict__ dst,
                               int* __restrict__ cur, int* __restrict__ csr) {
    int i = blockIdx.x * 256 + threadIdx.x;
    if (i >= TOTE) return;
    int s = (i < EE) ? src[i] : (i - EE);
    int d = (i < EE) ? dst[i] : (i - EE);
    int pos = atomicAdd(&cur[d], 1);
    csr[pos] = s;
}

// ---------------------------------------------------------------- GAT node kernel
// ONE WAVE PER NODE, fused online softmax, 1-deep software prefetch of the
// next edge's source row.
#define GAT_WPB 4
__global__ void gat_node_kernel(const float* __restrict__ xl, const float* __restrict__ xr,
                                const float* __restrict__ att, const float* __restrict__ bias,
                                const int* __restrict__ off, const int* __restrict__ csr,
                                float* __restrict__ h) {
    const int wave = threadIdx.x >> 6;
    const int lane = threadIdx.x & 63;
    const int n = blockIdx.x * GAT_WPB + wave;
    if (n >= NN) return;

    const float4* xr4 = (const float4*)(xr + (size_t)n * DHX);
    const float4* att4 = (const float4*)att;
    const float4 xr0 = xr4[lane],      xr1 = xr4[lane + 64];
    const float4 at0 = att4[lane],     at1 = att4[lane + 64];

    const int o0 = off[n], o1 = off[n + 1];

    float4 a0 = {0.f, 0.f, 0.f, 0.f}, a1 = {0.f, 0.f, 0.f, 0.f};
    float m = -INFINITY, den = 0.f;

    {
        const int s0 = csr[o0];
        const float4* p0 = (const float4*)(xl + (size_t)s0 * DHX);
        float4 nx0 = p0[lane], nx1 = p0[lane + 64];
        for (int e = o0; e < o1; e++) {
            const float4 x0 = nx0, x1 = nx1;
            if (e + 1 < o1) {
                const int s2 = csr[e + 1];
                const float4* p2 = (const float4*)(xl + (size_t)s2 * DHX);
                nx0 = p2[lane];
                nx1 = p2[lane + 64];
            }
            float v;
            {
                float4 l0, l1;
                l0.x = x0.x + xr0.x; l0.y = x0.y + xr0.y; l0.z = x0.z + xr0.z; l0.w = x0.w + xr0.w;
                l1.x = x1.x + xr1.x; l1.y = x1.y + xr1.y; l1.z = x1.z + xr1.z; l1.w = x1.w + xr1.w;
                l0.x = (l0.x > 0.f) ? l0.x : 0.2f * l0.x;
                l0.y = (l0.y > 0.f) ? l0.y : 0.2f * l0.y;
                l0.z = (l0.z > 0.f) ? l0.z : 0.2f * l0.z;
                l0.w = (l0.w > 0.f) ? l0.w : 0.2f * l0.w;
                l1.x = (l1.x > 0.f) ? l1.x : 0.2f * l1.x;
                l1.y = (l1.y > 0.f) ? l1.y : 0.2f * l1.y;
                l1.z = (l1.z > 0.f) ? l1.z : 0.2f * l1.z;
                l1.w = (l1.w > 0.f) ? l1.w : 0.2f * l1.w;
                v  = l0.x * at0.x + l0.y * at0.y + l0.z * at0.z + l0.w * at0.w;
                v += l1.x * at1.x + l1.y * at1.y + l1.z * at1.z + l1.w * at1.w;
            }
            #pragma unroll
            for (int sft = 32; sft; sft >>= 1) v += __shfl_xor(v, sft, 64);
            if (v > m) {
                const float r = expf(m - v);   // first edge: exp(-inf) = 0
                den *= r;
                a0.x *= r; a0.y *= r; a0.z *= r; a0.w *= r;
                a1.x *= r; a1.y *= r; a1.z *= r; a1.w *= r;
                m = v;
            }
            const float p = expf(v - m);
            den += p;
            a0.x += p * x0.x; a0.y += p * x0.y; a0.z += p * x0.z; a0.w += p * x0.w;
            a1.x += p * x1.x; a1.y += p * x1.y; a1.z += p * x1.z; a1.w += p * x1.w;
        }
    }

    const float inv = 1.f / den;
    const float4 b0 = ((const float4*)bias)[lane];
    const float4 b1 = ((const float4*)bias)[lane + 64];
    float4 o0v, o1v;
    o0v.x = fmaxf(a0.x * inv + b0.x, 0.f);
    o0v.y = fmaxf(a0.y * inv + b0.y, 0.f);
    o0v.z = fmaxf(a0.z * inv + b0.z, 0.f);
    o0v.w = fmaxf(a0.w * inv + b0.w, 0.f);
    o1v.x = fmaxf(a1.x * inv + b1.x, 0.f);
    o1v.y = fmaxf(a1.y * inv + b1.y, 0.f);
    o1v.z = fmaxf(a1.z * inv + b1.z, 0.f);
    o1v.w = fmaxf(a1.w * inv + b1.w, 0.f);
    float4* h4 = (float4*)(h + (size_t)n * DHX);
    h4[lane] = o0v;
    h4[lane + 64] = o1v;
}

// ---------------------------------------------------------------- BatchNorm stats
#define BN_GRID 625   // NN / 16
template <int C>
__global__ void bn_stats_kernel(const float* __restrict__ x, float* __restrict__ partial) {
    constexpr int G = C / 4;
    constexpr int S = 256 / G;
    constexpr int IT = 16 / S;
    const int t = threadIdx.x;
    const int cg = t & (G - 1);
    const int sub = t / G;
    const size_t r0 = (size_t)blockIdx.x * 16 + sub;
    float4 s = {0.f, 0.f, 0.f, 0.f}, q = {0.f, 0.f, 0.f, 0.f};
    #pragma unroll
    for (int i = 0; i < IT; i++) {
        const float4 v = *(const float4*)&x[(r0 + (size_t)i * S) * C + cg * 4];
        s.x += v.x; s.y += v.y; s.z += v.z; s.w += v.w;
        q.x += v.x * v.x; q.y += v.y * v.y; q.z += v.z * v.z; q.w += v.w * v.w;
    }
    __shared__ float ls[2048];
    float* lsub = ls + sub * 2 * C;
    *(float4*)&lsub[cg * 4] = s;
    *(float4*)&lsub[C + cg * 4] = q;
    __syncthreads();
    for (int k = t; k < 2 * C; k += 256) {
        float acc = 0.f;
        #pragma unroll
        for (int ss = 0; ss < S; ss++) acc += ls[ss * 2 * C + k];
        partial[(size_t)blockIdx.x * 2 * C + k] = acc;
    }
}

template <int C>
__global__ void bn_affine_kernel(const float* __restrict__ partial,
                                 const float* __restrict__ g, const float* __restrict__ b,
                                 float* __restrict__ scale, float* __restrict__ shift,
                                 float invM) {
    const int c = blockIdx.x;
    const int t = threadIdx.x;
    float s = 0.f, q = 0.f;
    for (int p = t; p < BN_GRID; p += 256) {
        s += partial[(size_t)p * 2 * C + c];
        q += partial[(size_t)p * 2 * C + C + c];
    }
    #pragma unroll
    for (int sh = 32; sh; sh >>= 1) {
        s += __shfl_xor(s, sh, 64);
        q += __shfl_xor(q, sh, 64);
    }
    __shared__ float ws[8];
    const int lane = t & 63, w = t >> 6;
    if (lane == 0) { ws[w] = s; ws[4 + w] = q; }
    __syncthreads();
    if (t == 0) {
        s = ws[0] + ws[1] + ws[2] + ws[3];
        q = ws[4] + ws[5] + ws[6] + ws[7];
        float mu = s * invM;
        float var = q * invM - mu * mu;
        float sc = g[c] * rsqrtf(var + BN_EPS);
        scale[c] = sc;
        shift[c] = b[c] - mu * sc;
    }
}

// ---------------------------------------------------------------- head output
__global__ void head_out_kernel(const float* __restrict__ z3, float* __restrict__ out, int M) {
    int r = blockIdx.x * 256 + threadIdx.x;
    if (r >= M) return;
    float v[DOUTX];
    float mx = -INFINITY;
    #pragma unroll
    for (int i = 0; i < DOUTX; i++) { v[i] = z3[(size_t)r * DOUTX + i]; mx = fmaxf(mx, v[i]); }
    float s = 0.f;
    #pragma unroll
    for (int i = 0; i < DOUTX; i++) s += expf(v[i] - mx);
    float lse = mx + logf(s);
    #pragma unroll
    for (int i = 0; i < DOUTX; i++) out[(size_t)r * DOUTX + i] = 1.f / (1.f + expf(-v[i]));
    #pragma unroll
    for (int i = 0; i < DOUTX; i++) out[(size_t)(M * DOUTX) + (size_t)r * DOUTX + i] = v[i] - lse;
}

// ---------------------------------------------------------------- launch
extern "C" void kernel_launch(void* const* d_in, const int* in_sizes, int n_in,
                              void* d_out, int out_size, void* d_ws, size_t ws_size,
                              hipStream_t stream) {
    // Only stream-1 inputs are live (stream 0's h is overwritten; pooling/batch/train dead).
    const float* data1  = (const float*)d_in[11];
    const int*   ei1    = (const int*)d_in[12];   // [2, E]: row0 = src, row1 = dst
    const float* Wl1    = (const float*)d_in[14];
    const float* bl1    = (const float*)d_in[15];
    const float* Wr1    = (const float*)d_in[16];
    const float* br1    = (const float*)d_in[17];
    const float* att1   = (const float*)d_in[18];
    const float* bias1  = (const float*)d_in[19];
    const float* gamma1 = (const float*)d_in[20];
    const float* beta1  = (const float*)d_in[21];
    const float* W1  = (const float*)d_in[22];
    const float* b1  = (const float*)d_in[23];
    const float* g1  = (const float*)d_in[24];
    const float* be1 = (const float*)d_in[25];
    const float* W2  = (const float*)d_in[26];
    const float* b2  = (const float*)d_in[27];
    const float* g2  = (const float*)d_in[28];
    const float* be2 = (const float*)d_in[29];
    const float* W3  = (const float*)d_in[30];
    const float* b3  = (const float*)d_in[31];

    const int* e_src = ei1;
    const int* e_dst = ei1 + EE;

    // ---- workspace layout (floats)
    float* fws = (float*)d_ws;
    float* xl = fws;                         // 5,120,000
    float* xr = fws + 5120000;               // 5,120,000
    float* h  = fws + 10240000;              // 5,120,000
    int* ibase = (int*)(fws + 15360000);
    int* deg   = ibase;                      // 10,000
    int* offs  = ibase + 10000;              // 10,001
    int* cur   = ibase + 20016;              // 10,000
    int* csr   = ibase + 30016;              // 170,000
    float* scale   = fws + 15625600;         // 512
    float* shift   = fws + 15626112;         // 512
    // aliases (producers/consumers don't overlap in time)
    float* z1 = xr;                          // [10000,256]
    float* z2 = xl;                          // [10000,128]
    float* z3 = xl + 4000000;                // [10000,16]
    float* part_h  = xl;                     // BN(h):  xl consumed by gat; z2 not yet written
    float* part_z1 = xl;                     // BN(z1): read before z2 GEMM writes xl
    float* part_z2 = h;                      // BN(z2): h consumed by z1 GEMM already
    float* out = (float*)d_out;

    dim3 blk(256);
    const int mB = (NN + 63) / 64;           // 157 m-strips
    const int sgc = (mB + 7) / 8;            // 20 strip-groups per XCD slot

    // ---- xl = x @ Wl + bl ; xr = x @ Wr + br   (K=128, N=512, nB=8)
    hipLaunchKernelGGL((gemm4_kernel<false, false>), dim3(8 * sgc * 8), blk, 0, stream,
                       data1, Wl1, bl1, nullptr, nullptr, xl, NN, DINX, DHX, mB, 8);
    hipLaunchKernelGGL((gemm4_kernel<false, false>), dim3(8 * sgc * 8), blk, 0, stream,
                       data1, Wr1, br1, nullptr, nullptr, xr, NN, DINX, DHX, mB, 8);

    // ---- CSR by destination (incl. self-loops)
    hipMemsetAsync(deg, 0, NN * sizeof(int), stream);
    hipLaunchKernelGGL(deg_kernel, dim3((TOTE + 255) / 256), blk, 0, stream, e_dst, deg);
    hipLaunchKernelGGL(scan_kernel, dim3(1), dim3(1024), 0, stream, deg, offs, cur, NN);
    hipLaunchKernelGGL(scatter_kernel, dim3((TOTE + 255) / 256), blk, 0, stream, e_src, e_dst, cur, csr);

    // ---- GATv2 aggregation + bias + relu -> h (one wave per node, prefetched)
    hipLaunchKernelGGL(gat_node_kernel, dim3((NN + GAT_WPB - 1) / GAT_WPB), blk, 0, stream,
                       xl, xr, att1, bias1, offs, csr, h);

    // ---- BN(h) stats -> scale/shift (application fused into next GEMM)
    hipLaunchKernelGGL((bn_stats_kernel<512>), dim3(BN_GRID), blk, 0, stream, h, part_h);
    hipLaunchKernelGGL((bn_affine_kernel<512>), dim3(512), blk, 0, stream, part_h, gamma1, beta1, scale, shift, 1.f / NN);

    // ---- z1 = relu((h∘BN) @ W1 + b1)   (K=512, N=256, nB=4)
    hipLaunchKernelGGL((gemm4_kernel<true, true>), dim3(8 * sgc * 4), blk, 0, stream,
                       h, W1, b1, scale, shift, z1, NN, 512, 256, mB, 4);
    hipLaunchKernelGGL((bn_stats_kernel<256>), dim3(BN_GRID), blk, 0, stream, z1, part_z1);
    hipLaunchKernelGGL((bn_affine_kernel<256>), dim3(256), blk, 0, stream, part_z1, g1, be1, scale, shift, 1.f / NN);

    // ---- z2 = relu((z1∘BN) @ W2 + b2)   (K=256, N=128, nB=2)
    hipLaunchKernelGGL((gemm4_kernel<true, true>), dim3(8 * sgc * 2), blk, 0, stream,
                       z1, W2, b2, scale, shift, z2, NN, 256, 128, mB, 2);
    hipLaunchKernelGGL((bn_stats_kernel<128>), dim3(BN_GRID), blk, 0, stream, z2, part_z2);
    hipLaunchKernelGGL((bn_affine_kernel<128>), dim3(128), blk, 0, stream, part_z2, g2, be2, scale, shift, 1.f / NN);

    // ---- z3 = (z2∘BN) @ W3 + b3 ; sigmoid + log_softmax   (K=128, N=16, nB=1)
    hipLaunchKernelGGL((gemm4_kernel<false, true>), dim3(8 * sgc * 1), blk, 0, stream,
                       z2, W3, b3, scale, shift, z3, NN, 128, DOUTX, mB, 1);
    hipLaunchKernelGGL(head_out_kernel, dim3((NN + 255) / 256), blk, 0, stream, z3, out, NN);

    (void)in_sizes; (void)n_in; (void)out_size; (void)ws_size;
}

// Round 13
// 366.287 us; speedup vs baseline: 1.0795x; 1.0012x over previous
//
#include <hip/hip_runtime.h>
#include <cmath>

#define NN 10000
#define DINX 128
#define DHX 512
#define EE 160000
#define TOTE (EE + NN)
#define DOUTX 16
#define BN_EPS 1e-5f

// ---------------------------------------------------------------- GEMM v4
// C[M,Nn] = (A∘BN?)[M,K] @ B[K,Nn] + bias (optional relu). K mult of 32.
// 64x64 tile, 256 threads, 4x4 contiguous outputs/thread (2x ds_read_b128/kk).
// XCD-grouped flat grid + register prefetch double-buffer.
template <bool RELU, bool BNA>
__global__ void gemm4_kernel(const float* __restrict__ A, const float* __restrict__ B,
                             const float* __restrict__ bias,
                             const float* __restrict__ sA, const float* __restrict__ tA,
                             float* __restrict__ C, int M, int K, int Nn,
                             int mB, int nB) {
    const int bid = blockIdx.x;
    const int x = bid & 7;
    const int rest = bid >> 3;
    const int sg = rest / nB;
    const int nblk = rest - sg * nB;
    const int mstrip = x + (sg << 3);
    if (mstrip >= mB) return;
    const int mBase = mstrip * 64;
    const int nBase = nblk * 64;

    __shared__ float As[32][68];   // [k][m]
    __shared__ float Bs[32][68];   // [k][n]
    const int t = threadIdx.x;
    const int tx = t & 15, ty = t >> 4;

    float4 ra[2], rb[2];

    auto loadA = [&](int k0, int i) -> float4 {
        int idx = t + i * 256;
        int r = idx >> 3;           // m 0..63
        int c4 = idx & 7;           // k-group
        int gm = mBase + r;
        int kc = k0 + c4 * 4;
        float4 v = {0.f, 0.f, 0.f, 0.f};
        if (gm < M) v = *(const float4*)&A[(size_t)gm * K + kc];
        if (BNA) {
            v.x = v.x * sA[kc + 0] + tA[kc + 0];
            v.y = v.y * sA[kc + 1] + tA[kc + 1];
            v.z = v.z * sA[kc + 2] + tA[kc + 2];
            v.w = v.w * sA[kc + 3] + tA[kc + 3];
        }
        return v;
    };
    auto loadB = [&](int k0, int i) -> float4 {
        int idx = t + i * 256;
        int kr = idx >> 4;          // k 0..31
        int nc4 = idx & 15;         // n-group
        int gn = nBase + nc4 * 4;
        float4 v = {0.f, 0.f, 0.f, 0.f};
        if (gn + 3 < Nn) v = *(const float4*)&B[(size_t)(k0 + kr) * Nn + gn];
        return v;
    };

    // prefetch tile 0
    #pragma unroll
    for (int i = 0; i < 2; i++) { ra[i] = loadA(0, i); rb[i] = loadB(0, i); }

    float acc[4][4] = {};
    for (int k0 = 0; k0 < K; k0 += 32) {
        // write staged registers to LDS
        #pragma unroll
        for (int i = 0; i < 2; i++) {
            int idx = t + i * 256;
            int r = idx >> 3, c4 = idx & 7;
            As[c4 * 4 + 0][r] = ra[i].x;
            As[c4 * 4 + 1][r] = ra[i].y;
            As[c4 * 4 + 2][r] = ra[i].z;
            As[c4 * 4 + 3][r] = ra[i].w;
        }
        #pragma unroll
        for (int i = 0; i < 2; i++) {
            int idx = t + i * 256;
            int kr = idx >> 4, nc4 = idx & 15;
            *(float4*)&Bs[kr][nc4 * 4] = rb[i];
        }
        __syncthreads();
        // issue next tile's global loads (latency hides under FMAs below)
        if (k0 + 32 < K) {
            #pragma unroll
            for (int i = 0; i < 2; i++) { ra[i] = loadA(k0 + 32, i); rb[i] = loadB(k0 + 32, i); }
        }
        // compute
        #pragma unroll
        for (int kk = 0; kk < 32; kk++) {
            float4 a = *(const float4*)&As[kk][ty * 4];
            float4 b = *(const float4*)&Bs[kk][tx * 4];
            float av[4] = {a.x, a.y, a.z, a.w};
            float bv[4] = {b.x, b.y, b.z, b.w};
            #pragma unroll
            for (int i = 0; i < 4; i++)
                #pragma unroll
                for (int j = 0; j < 4; j++) acc[i][j] += av[i] * bv[j];
        }
        __syncthreads();
    }
    const int gn0 = nBase + tx * 4;
    #pragma unroll
    for (int i = 0; i < 4; i++) {
        int gm = mBase + ty * 4 + i;
        if (gm >= M) continue;
        if (gn0 + 3 < Nn) {
            float4 v;
            v.x = acc[i][0] + bias[gn0 + 0];
            v.y = acc[i][1] + bias[gn0 + 1];
            v.z = acc[i][2] + bias[gn0 + 2];
            v.w = acc[i][3] + bias[gn0 + 3];
            if (RELU) {
                v.x = fmaxf(v.x, 0.f); v.y = fmaxf(v.y, 0.f);
                v.z = fmaxf(v.z, 0.f); v.w = fmaxf(v.w, 0.f);
            }
            *(float4*)&C[(size_t)gm * Nn + gn0] = v;
        } else {
            #pragma unroll
            for (int j = 0; j < 4; j++) {
                int gn = gn0 + j;
                if (gn >= Nn) continue;
                float v = acc[i][j] + bias[gn];
                if (RELU) v = fmaxf(v, 0.f);
                C[(size_t)gm * Nn + gn] = v;
            }
        }
    }
}

// ---------------------------------------------------------------- CSR build
__global__ void deg_kernel(const int* __restrict__ dst, int* __restrict__ deg) {
    int i = blockIdx.x * 256 + threadIdx.x;
    if (i >= TOTE) return;
    int d = (i < EE) ? dst[i] : (i - EE);
    atomicAdd(&deg[d], 1);
}

// Register-blocked single-block scan: 1024 threads x 10 elements each.
#define SCAN_PER 10
__global__ void scan_kernel(const int* __restrict__ deg, int* __restrict__ off,
                            int* __restrict__ cur, int n) {
    const int t = threadIdx.x;          // 0..1023
    const int lane = t & 63, w = t >> 6;
    const int base = t * SCAN_PER;
    int v[SCAN_PER];
    int s = 0;
    #pragma unroll
    for (int i = 0; i < SCAN_PER; i++) {
        int idx = base + i;
        int d = (idx < n) ? deg[idx] : 0;
        s += d;
        v[i] = s;                        // per-thread inclusive scan
    }
    int x = s;
    #pragma unroll
    for (int sh = 1; sh < 64; sh <<= 1) {
        int y = __shfl_up(x, sh, 64);
        if (lane >= sh) x += y;
    }
    __shared__ int wsum[16];
    if (lane == 63) wsum[w] = x;
    __syncthreads();
    int wpre = 0;
    for (int i = 0; i < w; i++) wpre += wsum[i];
    const int excl = wpre + x - s;
    #pragma unroll
    for (int i = 0; i < SCAN_PER; i++) {
        int idx = base + i;
        if (idx < n) {
            off[idx + 1] = excl + v[i];
            cur[idx] = excl + (i ? v[i - 1] : 0);
        }
    }
    if (t == 0) off[0] = 0;
}

__global__ void scatter_kernel(const int* __restrict__ src, const int* __restrict__ dst,
                               int* __restrict__ cur, int* __restrict__ csr) {
    int i = blockIdx.x * 256 + threadIdx.x;
    if (i >= TOTE) return;
    int s = (i < EE) ? src[i] : (i - EE);
    int d = (i < EE) ? dst[i] : (i - EE);
    int pos = atomicAdd(&cur[d], 1);
    csr[pos] = s;
}

// ---------------------------------------------------------------- GAT node kernel v3
// ONE WAVE PER NODE, fused online softmax. 2-edge paired processing with
// 2-pair-deep prefetch: 4 source rows (16 float4 loads/wave) in flight,
// doubling memory-level parallelism vs v2 (kernel measured 86% fetch-bound:
// 150MB L2-miss @2.9TB/s of 60us). The two logit dot+shfl-reduce chains are
// independent and interleave on the VALU; softmax state update stays ordered.
#define GAT_WPB 4
__global__ void gat_node_kernel(const float* __restrict__ xl, const float* __restrict__ xr,
                                const float* __restrict__ att, const float* __restrict__ bias,
                                const int* __restrict__ off, const int* __restrict__ csr,
                                float* __restrict__ h) {
    const int wave = threadIdx.x >> 6;
    const int lane = threadIdx.x & 63;
    const int n = blockIdx.x * GAT_WPB + wave;
    if (n >= NN) return;

    const float4* xr4 = (const float4*)(xr + (size_t)n * DHX);
    const float4* att4 = (const float4*)att;
    const float4 xr0 = xr4[lane],      xr1 = xr4[lane + 64];
    const float4 at0 = att4[lane],     at1 = att4[lane + 64];

    const int o0 = off[n], o1 = off[n + 1];
    const int last = o1 - 1;

    float4 a0 = {0.f, 0.f, 0.f, 0.f}, a1 = {0.f, 0.f, 0.f, 0.f};
    float m = -INFINITY, den = 0.f;

    // lane-partial logit for one row pair (pre-reduce)
    auto logit_part = [&](const float4& x0, const float4& x1) -> float {
        float4 l0, l1;
        l0.x = x0.x + xr0.x; l0.y = x0.y + xr0.y; l0.z = x0.z + xr0.z; l0.w = x0.w + xr0.w;
        l1.x = x1.x + xr1.x; l1.y = x1.y + xr1.y; l1.z = x1.z + xr1.z; l1.w = x1.w + xr1.w;
        l0.x = (l0.x > 0.f) ? l0.x : 0.2f * l0.x;
        l0.y = (l0.y > 0.f) ? l0.y : 0.2f * l0.y;
        l0.z = (l0.z > 0.f) ? l0.z : 0.2f * l0.z;
        l0.w = (l0.w > 0.f) ? l0.w : 0.2f * l0.w;
        l1.x = (l1.x > 0.f) ? l1.x : 0.2f * l1.x;
        l1.y = (l1.y > 0.f) ? l1.y : 0.2f * l1.y;
        l1.z = (l1.z > 0.f) ? l1.z : 0.2f * l1.z;
        l1.w = (l1.w > 0.f) ? l1.w : 0.2f * l1.w;
        float v;
        v  = l0.x * at0.x + l0.y * at0.y + l0.z * at0.z + l0.w * at0.w;
        v += l1.x * at1.x + l1.y * at1.y + l1.z * at1.z + l1.w * at1.w;
        return v;
    };
    // online softmax + weighted accumulation for one edge (v wave-uniform)
    auto update = [&](float v, const float4& x0, const float4& x1) {
        if (v > m) {
            const float r = expf(m - v);   // first edge: exp(-inf) = 0
            den *= r;
            a0.x *= r; a0.y *= r; a0.z *= r; a0.w *= r;
            a1.x *= r; a1.y *= r; a1.z *= r; a1.w *= r;
            m = v;
        }
        const float p = expf(v - m);
        den += p;
        a0.x += p * x0.x; a0.y += p * x0.y; a0.z += p * x0.z; a0.w += p * x0.w;
        a1.x += p * x1.x; a1.y += p * x1.y; a1.z += p * x1.z; a1.w += p * x1.w;
    };
    // clamped-index row fetch (wave-uniform idx; duplicate loads are harmless)
    auto rowp = [&](int e) -> const float4* {
        const int s = csr[min(e, last)];
        return (const float4*)(xl + (size_t)s * DHX);
    };

    // pair 0 (current) and pair 1 (next) in flight: 4 rows, 16 loads
    const float4* p;
    p = rowp(o0 + 0);  float4 c0x0 = p[lane], c0x1 = p[lane + 64];
    p = rowp(o0 + 1);  float4 c1x0 = p[lane], c1x1 = p[lane + 64];
    p = rowp(o0 + 2);  float4 n0x0 = p[lane], n0x1 = p[lane + 64];
    p = rowp(o0 + 3);  float4 n1x0 = p[lane], n1x1 = p[lane + 64];

    for (int e = o0; e < o1; e += 2) {
        // two independent logit chains (interleaved by scheduler)
        float v0 = logit_part(c0x0, c0x1);
        float v1 = logit_part(c1x0, c1x1);
        #pragma unroll
        for (int sft = 32; sft; sft >>= 1) {
            v0 += __shfl_xor(v0, sft, 64);
            v1 += __shfl_xor(v1, sft, 64);
        }
        // ordered softmax updates
        update(v0, c0x0, c0x1);
        if (e + 1 < o1) update(v1, c1x0, c1x1);
        // rotate pipeline and prefetch pair e+4, e+5
        c0x0 = n0x0; c0x1 = n0x1; c1x0 = n1x0; c1x1 = n1x1;
        if (e + 4 < o1) {
            p = rowp(e + 4);  n0x0 = p[lane];  n0x1 = p[lane + 64];
            p = rowp(e + 5);  n1x0 = p[lane];  n1x1 = p[lane + 64];
        }
    }

    const float inv = 1.f / den;
    const float4 b0 = ((const float4*)bias)[lane];
    const float4 b1 = ((const float4*)bias)[lane + 64];
    float4 o0v, o1v;
    o0v.x = fmaxf(a0.x * inv + b0.x, 0.f);
    o0v.y = fmaxf(a0.y * inv + b0.y, 0.f);
    o0v.z = fmaxf(a0.z * inv + b0.z, 0.f);
    o0v.w = fmaxf(a0.w * inv + b0.w, 0.f);
    o1v.x = fmaxf(a1.x * inv + b1.x, 0.f);
    o1v.y = fmaxf(a1.y * inv + b1.y, 0.f);
    o1v.z = fmaxf(a1.z * inv + b1.z, 0.f);
    o1v.w = fmaxf(a1.w * inv + b1.w, 0.f);
    float4* h4 = (float4*)(h + (size_t)n * DHX);
    h4[lane] = o0v;
    h4[lane + 64] = o1v;
}

// ---------------------------------------------------------------- BatchNorm stats
#define BN_GRID 625   // NN / 16
template <int C>
__global__ void bn_stats_kernel(const float* __restrict__ x, float* __restrict__ partial) {
    constexpr int G = C / 4;
    constexpr int S = 256 / G;
    constexpr int IT = 16 / S;
    const int t = threadIdx.x;
    const int cg = t & (G - 1);
    const int sub = t / G;
    const size_t r0 = (size_t)blockIdx.x * 16 + sub;
    float4 s = {0.f, 0.f, 0.f, 0.f}, q = {0.f, 0.f, 0.f, 0.f};
    #pragma unroll
    for (int i = 0; i < IT; i++) {
        const float4 v = *(const float4*)&x[(r0 + (size_t)i * S) * C + cg * 4];
        s.x += v.x; s.y += v.y; s.z += v.z; s.w += v.w;
        q.x += v.x * v.x; q.y += v.y * v.y; q.z += v.z * v.z; q.w += v.w * v.w;
    }
    __shared__ float ls[2048];
    float* lsub = ls + sub * 2 * C;
    *(float4*)&lsub[cg * 4] = s;
    *(float4*)&lsub[C + cg * 4] = q;
    __syncthreads();
    for (int k = t; k < 2 * C; k += 256) {
        float acc = 0.f;
        #pragma unroll
        for (int ss = 0; ss < S; ss++) acc += ls[ss * 2 * C + k];
        partial[(size_t)blockIdx.x * 2 * C + k] = acc;
    }
}

template <int C>
__global__ void bn_affine_kernel(const float* __restrict__ partial,
                                 const float* __restrict__ g, const float* __restrict__ b,
                                 float* __restrict__ scale, float* __restrict__ shift,
                                 float invM) {
    const int c = blockIdx.x;
    const int t = threadIdx.x;
    float s = 0.f, q = 0.f;
    for (int p = t; p < BN_GRID; p += 256) {
        s += partial[(size_t)p * 2 * C + c];
        q += partial[(size_t)p * 2 * C + C + c];
    }
    #pragma unroll
    for (int sh = 32; sh; sh >>= 1) {
        s += __shfl_xor(s, sh, 64);
        q += __shfl_xor(q, sh, 64);
    }
    __shared__ float ws[8];
    const int lane = t & 63, w = t >> 6;
    if (lane == 0) { ws[w] = s; ws[4 + w] = q; }
    __syncthreads();
    if (t == 0) {
        s = ws[0] + ws[1] + ws[2] + ws[3];
        q = ws[4] + ws[5] + ws[6] + ws[7];
        float mu = s * invM;
        float var = q * invM - mu * mu;
        float sc = g[c] * rsqrtf(var + BN_EPS);
        scale[c] = sc;
        shift[c] = b[c] - mu * sc;
    }
}

// ---------------------------------------------------------------- head output
__global__ void head_out_kernel(const float* __restrict__ z3, float* __restrict__ out, int M) {
    int r = blockIdx.x * 256 + threadIdx.x;
    if (r >= M) return;
    float v[DOUTX];
    float mx = -INFINITY;
    #pragma unroll
    for (int i = 0; i < DOUTX; i++) { v[i] = z3[(size_t)r * DOUTX + i]; mx = fmaxf(mx, v[i]); }
    float s = 0.f;
    #pragma unroll
    for (int i = 0; i < DOUTX; i++) s += expf(v[i] - mx);
    float lse = mx + logf(s);
    #pragma unroll
    for (int i = 0; i < DOUTX; i++) out[(size_t)r * DOUTX + i] = 1.f / (1.f + expf(-v[i]));
    #pragma unroll
    for (int i = 0; i < DOUTX; i++) out[(size_t)(M * DOUTX) + (size_t)r * DOUTX + i] = v[i] - lse;
}

// ---------------------------------------------------------------- launch
extern "C" void kernel_launch(void* const* d_in, const int* in_sizes, int n_in,
                              void* d_out, int out_size, void* d_ws, size_t ws_size,
                              hipStream_t stream) {
    // Only stream-1 inputs are live (stream 0's h is overwritten; pooling/batch/train dead).
    const float* data1  = (const float*)d_in[11];
    const int*   ei1    = (const int*)d_in[12];   // [2, E]: row0 = src, row1 = dst
    const float* Wl1    = (const float*)d_in[14];
    const float* bl1    = (const float*)d_in[15];
    const float* Wr1    = (const float*)d_in[16];
    const float* br1    = (const float*)d_in[17];
    const float* att1   = (const float*)d_in[18];
    const float* bias1  = (const float*)d_in[19];
    const float* gamma1 = (const float*)d_in[20];
    const float* beta1  = (const float*)d_in[21];
    const float* W1  = (const float*)d_in[22];
    const float* b1  = (const float*)d_in[23];
    const float* g1  = (const float*)d_in[24];
    const float* be1 = (const float*)d_in[25];
    const float* W2  = (const float*)d_in[26];
    const float* b2  = (const float*)d_in[27];
    const float* g2  = (const float*)d_in[28];
    const float* be2 = (const float*)d_in[29];
    const float* W3  = (const float*)d_in[30];
    const float* b3  = (const float*)d_in[31];

    const int* e_src = ei1;
    const int* e_dst = ei1 + EE;

    // ---- workspace layout (floats)
    float* fws = (float*)d_ws;
    float* xl = fws;                         // 5,120,000
    float* xr = fws + 5120000;               // 5,120,000
    float* h  = fws + 10240000;              // 5,120,000
    int* ibase = (int*)(fws + 15360000);
    int* deg   = ibase;                      // 10,000
    int* offs  = ibase + 10000;              // 10,001
    int* cur   = ibase + 20016;              // 10,000
    int* csr   = ibase + 30016;              // 170,000
    float* scale   = fws + 15625600;         // 512
    float* shift   = fws + 15626112;         // 512
    // aliases (producers/consumers don't overlap in time)
    float* z1 = xr;                          // [10000,256]
    float* z2 = xl;                          // [10000,128]
    float* z3 = xl + 4000000;                // [10000,16]
    float* part_h  = xl;                     // BN(h):  xl consumed by gat; z2 not yet written
    float* part_z1 = xl;                     // BN(z1): read before z2 GEMM writes xl
    float* part_z2 = h;                      // BN(z2): h consumed by z1 GEMM already
    float* out = (float*)d_out;

    dim3 blk(256);
    const int mB = (NN + 63) / 64;           // 157 m-strips
    const int sgc = (mB + 7) / 8;            // 20 strip-groups per XCD slot

    // ---- xl = x @ Wl + bl ; xr = x @ Wr + br   (K=128, N=512, nB=8)
    hipLaunchKernelGGL((gemm4_kernel<false, false>), dim3(8 * sgc * 8), blk, 0, stream,
                       data1, Wl1, bl1, nullptr, nullptr, xl, NN, DINX, DHX, mB, 8);
    hipLaunchKernelGGL((gemm4_kernel<false, false>), dim3(8 * sgc * 8), blk, 0, stream,
                       data1, Wr1, br1, nullptr, nullptr, xr, NN, DINX, DHX, mB, 8);

    // ---- CSR by destination (incl. self-loops)
    hipMemsetAsync(deg, 0, NN * sizeof(int), stream);
    hipLaunchKernelGGL(deg_kernel, dim3((TOTE + 255) / 256), blk, 0, stream, e_dst, deg);
    hipLaunchKernelGGL(scan_kernel, dim3(1), dim3(1024), 0, stream, deg, offs, cur, NN);
    hipLaunchKernelGGL(scatter_kernel, dim3((TOTE + 255) / 256), blk, 0, stream, e_src, e_dst, cur, csr);

    // ---- GATv2 aggregation + bias + relu -> h (one wave per node, 2-pair pipeline)
    hipLaunchKernelGGL(gat_node_kernel, dim3((NN + GAT_WPB - 1) / GAT_WPB), blk, 0, stream,
                       xl, xr, att1, bias1, offs, csr, h);

    // ---- BN(h) stats -> scale/shift (application fused into next GEMM)
    hipLaunchKernelGGL((bn_stats_kernel<512>), dim3(BN_GRID), blk, 0, stream, h, part_h);
    hipLaunchKernelGGL((bn_affine_kernel<512>), dim3(512), blk, 0, stream, part_h, gamma1, beta1, scale, shift, 1.f / NN);

    // ---- z1 = relu((h∘BN) @ W1 + b1)   (K=512, N=256, nB=4)
    hipLaunchKernelGGL((gemm4_kernel<true, true>), dim3(8 * sgc * 4), blk, 0, stream,
                       h, W1, b1, scale, shift, z1, NN, 512, 256, mB, 4);
    hipLaunchKernelGGL((bn_stats_kernel<256>), dim3(BN_GRID), blk, 0, stream, z1, part_z1);
    hipLaunchKernelGGL((bn_affine_kernel<256>), dim3(256), blk, 0, stream, part_z1, g1, be1, scale, shift, 1.f / NN);

    // ---- z2 = relu((z1∘BN) @ W2 + b2)   (K=256, N=128, nB=2)
    hipLaunchKernelGGL((gemm4_kernel<true, true>), dim3(8 * sgc * 2), blk, 0, stream,
                       z1, W2, b2, scale, shift, z2, NN, 256, 128, mB, 2);
    hipLaunchKernelGGL((bn_stats_kernel<128>), dim3(BN_GRID), blk, 0, stream, z2, part_z2);
    hipLaunchKernelGGL((bn_affine_kernel<128>), dim3(128), blk, 0, stream, part_z2, g2, be2, scale, shift, 1.f / NN);

    // ---- z3 = (z2∘BN) @ W3 + b3 ; sigmoid + log_softmax   (K=128, N=16, nB=1)
    hipLaunchKernelGGL((gemm4_kernel<false, true>), dim3(8 * sgc * 1), blk, 0, stream,
                       z2, W3, b3, scale, shift, z3, NN, 128, DOUTX, mB, 1);
    hipLaunchKernelGGL(head_out_kernel, dim3((NN + 255) / 256), blk, 0, stream, z3, out, NN);

    (void)in_sizes; (void)n_in; (void)out_size; (void)ws_size;
}